// Round 14
// baseline (429.247 us; speedup 1.0000x reference)
//
#include <hip/hip_runtime.h>
#include <hip/hip_fp16.h>

#define ND 56
#define HD 64
#define S1 60        // W1T row stride (words)
#define S2 68        // W2T row stride (words)
#define DEDD_H2 32   // dEdD row = 32 half2 = 64 halfs = 128B
#define ESUM_MAX 1024
#define FBLK 2048    // force grid blocks (max)

typedef float v4f __attribute__((ext_vector_type(4)));
typedef _Float16 v4h __attribute__((ext_vector_type(4)));

__global__ __launch_bounds__(256) void zero_kernel(float* __restrict__ p, int n) {
    int i = blockIdx.x * 256 + threadIdx.x;
    if (i < n) p[i] = 0.f;
}

// Persistent MLP fwd+bwd (round-9 version, unchanged).
__global__ __launch_bounds__(256) void mlp_kernel(
    const float* __restrict__ x, const int* __restrict__ indices,
    const float* __restrict__ W1, const float* __restrict__ b1,
    const float* __restrict__ W2, const float* __restrict__ b2,
    const float* __restrict__ W3, const float* __restrict__ b3,
    float* __restrict__ e_out, __half2* __restrict__ dEdD,
    int natoms, int nconf)
{
    __shared__ float W1T[HD * S1 + 4];
    __shared__ float W2T[HD * S2];
    __shared__ float b1s[HD], b2s[HD], W3s[HD];
    __shared__ float xs[16 * ND];
    __shared__ float hbuf[4][4][HD];
    __shared__ float gbuf[4][4][HD];
    __shared__ float esum[ESUM_MAX];

    const int tid = threadIdx.x;
    for (int i = tid; i < ND * HD; i += 256) W1T[(i % HD) * S1 + (i / HD)] = W1[i];
    for (int i = tid; i < HD * HD; i += 256) W2T[(i % HD) * S2 + (i / HD)] = W2[i];
    for (int i = tid; i < ESUM_MAX; i += 256) esum[i] = 0.f;
    if (tid < HD) { b1s[tid] = b1[tid]; b2s[tid] = b2[tid]; W3s[tid] = W3[tid]; }
    __syncthreads();

    const int w = tid >> 6, lane = tid & 63;
    const float b3v = b3[0];
    const float b1v = b1s[lane], b2v = b2s[lane], w3v = W3s[lane];
    const int nGroups = (natoms + 15) >> 4;
    const bool ldsE = (nconf <= ESUM_MAX);

    for (int grp = blockIdx.x; grp < nGroups; grp += gridDim.x) {
        const int abase = grp * 16 + w * 4;

        if (lane < 56) {
            const int a = lane / 14;
            if (abase + a < natoms)
                reinterpret_cast<float4*>(xs + w * 4 * ND)[lane] =
                    reinterpret_cast<const float4*>(x)[(size_t)abase * 14 + lane];
        }

        float4 acc[4];
        #pragma unroll
        for (int a = 0; a < 4; ++a) acc[a] = float4{0.f, 0.f, 0.f, 0.f};
        #pragma unroll
        for (int i = 0; i < 14; ++i) {
            const float4 wv = *reinterpret_cast<const float4*>(&W1T[lane * S1 + 4 * i]);
            #pragma unroll
            for (int a = 0; a < 4; ++a) {
                const float4 xv = *reinterpret_cast<const float4*>(&xs[(w * 4 + a) * ND + 4 * i]);
                acc[a].x = fmaf(wv.x, xv.x, acc[a].x);
                acc[a].y = fmaf(wv.y, xv.y, acc[a].y);
                acc[a].z = fmaf(wv.z, xv.z, acc[a].z);
                acc[a].w = fmaf(wv.w, xv.w, acc[a].w);
            }
        }
        float z1[4], s1[4];
        #pragma unroll
        for (int a = 0; a < 4; ++a) {
            z1[a] = b1v + ((acc[a].x + acc[a].y) + (acc[a].z + acc[a].w));
            s1[a] = 1.f / (1.f + __expf(-z1[a]));
            hbuf[w][a][lane] = z1[a] * s1[a];
        }

        #pragma unroll
        for (int a = 0; a < 4; ++a) acc[a] = float4{0.f, 0.f, 0.f, 0.f};
        #pragma unroll
        for (int i = 0; i < 16; ++i) {
            const float4 wv = *reinterpret_cast<const float4*>(&W2T[lane * S2 + 4 * i]);
            #pragma unroll
            for (int a = 0; a < 4; ++a) {
                const float4 hv = *reinterpret_cast<const float4*>(&hbuf[w][a][4 * i]);
                acc[a].x = fmaf(wv.x, hv.x, acc[a].x);
                acc[a].y = fmaf(wv.y, hv.y, acc[a].y);
                acc[a].z = fmaf(wv.z, hv.z, acc[a].z);
                acc[a].w = fmaf(wv.w, hv.w, acc[a].w);
            }
        }
        float ev[4];
        #pragma unroll
        for (int a = 0; a < 4; ++a) {
            const float z2 = b2v + ((acc[a].x + acc[a].y) + (acc[a].z + acc[a].w));
            const float s2 = 1.f / (1.f + __expf(-z2));
            ev[a] = (z2 * s2) * w3v;
            gbuf[w][a][lane] = w3v * (s2 * (1.f + z2 * (1.f - s2)));
        }
        #pragma unroll
        for (int off = 32; off > 0; off >>= 1) {
            #pragma unroll
            for (int a = 0; a < 4; ++a) ev[a] += __shfl_xor(ev[a], off);
        }
        if (lane == 0) {
            #pragma unroll
            for (int a = 0; a < 4; ++a)
                if (abase + a < natoms) {
                    const int conf = indices[abase + a];
                    if (ldsE) atomicAdd(&esum[conf], ev[a] + b3v);
                    else      unsafeAtomicAdd(&e_out[conf], ev[a] + b3v);
                }
        }

        #pragma unroll
        for (int a = 0; a < 4; ++a) acc[a] = float4{0.f, 0.f, 0.f, 0.f};
        #pragma unroll
        for (int i = 0; i < 16; ++i) {
            const float w0 = W2T[(4 * i + 0) * S2 + lane];
            const float w1v = W2T[(4 * i + 1) * S2 + lane];
            const float w2v = W2T[(4 * i + 2) * S2 + lane];
            const float w3x = W2T[(4 * i + 3) * S2 + lane];
            #pragma unroll
            for (int a = 0; a < 4; ++a) {
                const float4 gv = *reinterpret_cast<const float4*>(&gbuf[w][a][4 * i]);
                acc[a].x = fmaf(w0, gv.x, acc[a].x);
                acc[a].y = fmaf(w1v, gv.y, acc[a].y);
                acc[a].z = fmaf(w2v, gv.z, acc[a].z);
                acc[a].w = fmaf(w3x, gv.w, acc[a].w);
            }
        }
        #pragma unroll
        for (int a = 0; a < 4; ++a) {
            const float dh1 = (acc[a].x + acc[a].y) + (acc[a].z + acc[a].w);
            hbuf[w][a][lane] = dh1 * (s1[a] * (1.f + z1[a] * (1.f - s1[a])));
        }

        #pragma unroll
        for (int a = 0; a < 4; ++a) acc[a] = float4{0.f, 0.f, 0.f, 0.f};
        #pragma unroll
        for (int i = 0; i < 16; ++i) {
            const float w0 = W1T[(4 * i + 0) * S1 + lane];
            const float w1v = W1T[(4 * i + 1) * S1 + lane];
            const float w2v = W1T[(4 * i + 2) * S1 + lane];
            const float w3x = W1T[(4 * i + 3) * S1 + lane];
            #pragma unroll
            for (int a = 0; a < 4; ++a) {
                const float4 gv = *reinterpret_cast<const float4*>(&hbuf[w][a][4 * i]);
                acc[a].x = fmaf(w0, gv.x, acc[a].x);
                acc[a].y = fmaf(w1v, gv.y, acc[a].y);
                acc[a].z = fmaf(w2v, gv.z, acc[a].z);
                acc[a].w = fmaf(w3x, gv.w, acc[a].w);
            }
        }
        #pragma unroll
        for (int a = 0; a < 4; ++a) {
            const float v  = (acc[a].x + acc[a].y) + (acc[a].z + acc[a].w);
            const float vh = __shfl_down(v, 1);
            if ((lane & 1) == 0 && lane < ND && abase + a < natoms)
                dEdD[(size_t)(abase + a) * DEDD_H2 + (lane >> 1)] =
                    __floats2half2_rn(v, vh);
        }
    }

    if (ldsE) {
        __syncthreads();
        for (int c = tid; c < nconf; c += 256) {
            const float v = esum[c];
            if (v != 0.f) unsafeAtomicAdd(&e_out[c], v);
        }
    }
}

// ---- force: 2-deep software pipeline ------------------------------------
// Batch = 4 rows/team (64 rows/block). Pipeline: LOAD(B) -> ATOMIC(A) ->
// LOAD(A') -> ATOMIC(B). In-order vmcnt retirement thus gives each atomic a
// full batch of loads+compute (~2 iterations) to complete before any wave
// waits on it. Arrays are indexed ONLY by fully-unrolled induction vars ->
// registers, no scratch.
struct FBatch {
    v4f uu[4];
    v4h hh[4];
    int cc[4];
    int jj[4];
};

__device__ __forceinline__ void fload(
    FBatch& B, int m0, int team, int sub, int mend,
    const float* __restrict__ xd, const int* __restrict__ xd_indx,
    const int* __restrict__ unique_j, const _Float16* __restrict__ dEdD)
{
    #pragma unroll
    for (int r = 0; r < 4; ++r) {
        const int m = m0 + 4 * team + r;
        if (m < mend) {
            if (sub < 14) {
                const int a = __builtin_nontemporal_load(xd_indx + 3 * (size_t)m);
                B.uu[r] = __builtin_nontemporal_load(
                    reinterpret_cast<const v4f*>(xd) + (size_t)m * 14 + sub);
                B.hh[r] = reinterpret_cast<const v4h*>(dEdD + ((size_t)a << 6))[sub];
            }
            if (sub == 0) {
                B.cc[r] = __builtin_nontemporal_load(xd_indx + 3 * (size_t)m + 2);
                B.jj[r] = __builtin_nontemporal_load(unique_j + m);
            }
        }
    }
}

__device__ __forceinline__ void fcompat(
    const FBatch& B, int m0, int team, int sub, int mend,
    float* __restrict__ out_f)
{
    #pragma unroll
    for (int r = 0; r < 4; ++r) {
        const int m = m0 + 4 * team + r;
        float p = 0.f;
        if (m < mend && sub < 14)
            p = fmaf(B.uu[r].x, (float)B.hh[r].x,
                fmaf(B.uu[r].y, (float)B.hh[r].y,
                fmaf(B.uu[r].z, (float)B.hh[r].z, B.uu[r].w * (float)B.hh[r].w)));
        p += __shfl_xor(p, 1);
        p += __shfl_xor(p, 2);
        p += __shfl_xor(p, 4);
        p += __shfl_xor(p, 8);
        if (m < mend && sub == 0)
            unsafeAtomicAdd(&out_f[(size_t)B.jj[r] * 3 + B.cc[r]], p);
    }
}

__global__ __launch_bounds__(256) void force_kernel(
    const float* __restrict__ xd,       // [M*ND]
    const int*   __restrict__ xd_indx,  // [M*3]
    const int*   __restrict__ unique_j, // [M]
    const _Float16* __restrict__ dEdD,  // [natoms*64] halfs
    float* __restrict__ out_f,          // [3*natoms] (pre-zeroed d_out region)
    int M, int CH)
{
    const int b = blockIdx.x, tid = threadIdx.x;
    const int team = tid >> 4, sub = tid & 15;   // 16 teams/block
    const int mstart = b * CH;
    const int mend   = min(mstart + CH, M);
    if (mstart >= mend) return;

    FBatch A = {}, B = {};

    fload(A, mstart, team, sub, mend, xd, xd_indx, unique_j, dEdD);
    for (int m0 = mstart; m0 < mend; m0 += 128) {
        const int m1 = m0 + 64;
        if (m1 < mend) fload(B, m1, team, sub, mend, xd, xd_indx, unique_j, dEdD);
        fcompat(A, m0, team, sub, mend, out_f);
        const int m2 = m0 + 128;
        if (m2 < mend) fload(A, m2, team, sub, mend, xd, xd_indx, unique_j, dEdD);
        if (m1 < mend) fcompat(B, m1, team, sub, mend, out_f);
    }
}

extern "C" void kernel_launch(void* const* d_in, const int* in_sizes, int n_in,
                              void* d_out, int out_size, void* d_ws, size_t ws_size,
                              hipStream_t stream) {
    const float* x        = (const float*)d_in[0];
    const float* xd       = (const float*)d_in[1];
    const int*   indices  = (const int*)d_in[2];
    const int*   xd_indx  = (const int*)d_in[4];
    const int*   unique_j = (const int*)d_in[5];
    const float* W1 = (const float*)d_in[6];
    const float* b1 = (const float*)d_in[7];
    const float* W2 = (const float*)d_in[8];
    const float* b2 = (const float*)d_in[9];
    const float* W3 = (const float*)d_in[10];
    const float* b3 = (const float*)d_in[11];

    const int natoms = in_sizes[0] / ND;
    const int M      = in_sizes[1] / ND;
    const int nconf  = in_sizes[3];

    float*    out_e = (float*)d_out;           // [nconf]
    float*    out_f = out_e + nconf;           // [3*natoms]
    __half2*  dEdD2 = (__half2*)d_ws;          // [natoms*32] half2 (6.4 MB)
    _Float16* dEdDh = (_Float16*)d_ws;

    // d_out is poisoned once before timing; zero it every call.
    zero_kernel<<<(out_size + 255) / 256, 256, 0, stream>>>((float*)d_out, out_size);

    const int nGroups = (natoms + 15) >> 4;
    const int mlpGrid = nGroups < 768 ? nGroups : 768;
    mlp_kernel<<<mlpGrid, 256, 0, stream>>>(
        x, indices, W1, b1, W2, b2, W3, b3, out_e, dEdD2, natoms, nconf);

    // CH rounded to a multiple of 128 (pipeline step = 2 batches of 64 rows)
    int CH = (M + FBLK - 1) / FBLK;
    CH = (CH + 127) & ~127;
    const int fGrid = (M + CH - 1) / CH;
    force_kernel<<<fGrid, 256, 0, stream>>>(
        xd, xd_indx, unique_j, dEdDh, out_f, M, CH);
}

// Round 15
// 273.758 us; speedup vs baseline: 1.5680x; 1.5680x over previous
//
#include <hip/hip_runtime.h>
#include <hip/hip_fp16.h>

#define ND 56
#define HD 64
#define DEDD_H2 32   // dEdD row = 64 halfs = 128B
#define ESUM_MAX 512
#define FBLK 2048
#define XROW 72      // xh row stride in f16 (16 rows x 72)

typedef float v4f __attribute__((ext_vector_type(4)));
typedef _Float16 v4h __attribute__((ext_vector_type(4)));
typedef _Float16 half8 __attribute__((ext_vector_type(8)));
typedef float f32x4 __attribute__((ext_vector_type(4)));

__device__ __forceinline__ unsigned pk2h(float a, float b) {
    unsigned short ha = __builtin_bit_cast(unsigned short, (_Float16)a);
    unsigned short hb = __builtin_bit_cast(unsigned short, (_Float16)b);
    return (unsigned)ha | ((unsigned)hb << 16);
}

__global__ __launch_bounds__(256) void zero_kernel(float* __restrict__ p, int n) {
    int i = blockIdx.x * 256 + threadIdx.x;
    if (i < n) p[i] = 0.f;
}

// MFMA MLP fwd+bwd: one wave = 16 atoms. Weights live in register B-frags
// (packed once via a pre-swizzled LDS staging area). Activations round-trip
// through a wave-private LDS buffer in A-frag layout. A and B are packed with
// the SAME (lanegroup,reg)->k map, so any HW k-permutation cancels.
__global__ __launch_bounds__(256, 2) void mlp_kernel(
    const float* __restrict__ x, const int* __restrict__ indices,
    const float* __restrict__ W1, const float* __restrict__ b1,
    const float* __restrict__ W2, const float* __restrict__ b2,
    const float* __restrict__ W3, const float* __restrict__ b3,
    float* __restrict__ e_out, _Float16* __restrict__ dEdD,
    int natoms, int nconf)
{
    __shared__ _Float16 wfrag[4][4096];      // 4 matrices, frag-linear order
    __shared__ _Float16 xh[4][16 * XROW];    // per-wave activation buffer
    __shared__ float esum[ESUM_MAX];

    const int tid = threadIdx.x;
    // ---- pack weight fragments (once per block) ----
    // frag linear r = ((ks*4+nt)*64 + lane)*8 + j ; k = ks*32+(lane>>4)*8+j ;
    // n = nt*16+(lane&15)
    for (int idx = tid; idx < 4 * 4096; idx += 256) {
        const int mat = idx >> 12;
        const int r   = idx & 4095;
        const int j  = r & 7;
        const int ln = (r >> 3) & 63;
        const int nt = (r >> 9) & 3;
        const int ks = r >> 11;
        const int k = ks * 32 + (ln >> 4) * 8 + j;
        const int n = nt * 16 + (ln & 15);
        float v;
        if (mat == 0)      v = (k < ND) ? W1[k * HD + n] : 0.f;  // B fwd1: W1[d][h]
        else if (mat == 1) v = W2[k * HD + n];                   // B fwd2: W2[k][h]
        else if (mat == 2) v = W2[n * HD + k];                   // B bwd1: W2^T
        else               v = (n < ND) ? W1[n * HD + k] : 0.f;  // B bwd2: W1^T
        wfrag[mat][r] = (_Float16)v;
    }
    for (int i = tid; i < ESUM_MAX; i += 256) esum[i] = 0.f;
    __syncthreads();

    const int w = tid >> 6, lane = tid & 63;
    const int col = lane & 15, g = lane >> 4;

    // ---- load persistent register B-frags (128 VGPRs) ----
    half8 wb[4][2][4];
    #pragma unroll
    for (int mat = 0; mat < 4; ++mat)
        #pragma unroll
        for (int ks = 0; ks < 2; ++ks)
            #pragma unroll
            for (int t = 0; t < 4; ++t)
                wb[mat][ks][t] = *reinterpret_cast<const half8*>(
                    &wfrag[mat][((ks * 4 + t) * 64 + lane) * 8]);

    float b1v[4], b2v[4], w3v[4];
    #pragma unroll
    for (int t = 0; t < 4; ++t) {
        b1v[t] = b1[t * 16 + col];
        b2v[t] = b2[t * 16 + col];
        w3v[t] = W3[t * 16 + col];
    }
    const float b3v = b3[0];
    const bool ldsE = (nconf <= ESUM_MAX);

    _Float16* xw = &xh[w][0];
    const int nGroups = (natoms + 15) >> 4;

    for (int grp = blockIdx.x * 4 + w; grp < nGroups; grp += gridDim.x * 4) {
        const int abase = grp * 16;

        // ---- stage x -> f16, A-frag-readable rows [atom][0..63] ----
        #pragma unroll
        for (int c = 0; c < 4; ++c) {
            const int v = lane * 4 + c * 256;      // 0..1023
            const int atom = v >> 6, d = v & 63;   // d multiple of 4
            unsigned long long u = 0ull;
            if (d < ND && abase + atom < natoms) {
                const v4f xv = *reinterpret_cast<const v4f*>(
                    &x[(size_t)(abase + atom) * ND + d]);
                u = (unsigned long long)pk2h(xv.x, xv.y)
                  | ((unsigned long long)pk2h(xv.z, xv.w) << 32);
            }
            *reinterpret_cast<unsigned long long*>(&xw[atom * XROW + d]) = u;
        }

        // ---- fwd1: z1 = X @ W1 + b1 ----
        f32x4 z1[4];
        #pragma unroll
        for (int t = 0; t < 4; ++t) z1[t] = f32x4{b1v[t], b1v[t], b1v[t], b1v[t]};
        #pragma unroll
        for (int ks = 0; ks < 2; ++ks) {
            const half8 a = *reinterpret_cast<const half8*>(
                &xw[col * XROW + g * 8 + ks * 32]);
            #pragma unroll
            for (int t = 0; t < 4; ++t)
                z1[t] = __builtin_amdgcn_mfma_f32_16x16x32_f16(a, wb[0][ks][t], z1[t], 0, 0, 0);
        }
        // h1 = silu(z1) -> xh  (C/D: col=lane&15, row=4*(lane>>4)+i)
        #pragma unroll
        for (int t = 0; t < 4; ++t)
            #pragma unroll
            for (int i = 0; i < 4; ++i) {
                const float z = z1[t][i];
                const float h = z / (1.f + __expf(-z));
                const float hn = __shfl_xor(h, 1);
                if ((lane & 1) == 0)
                    *reinterpret_cast<unsigned*>(
                        &xw[(4 * g + i) * XROW + t * 16 + col]) = pk2h(h, hn);
            }

        // ---- fwd2: z2 = H1 @ W2 + b2 ----
        f32x4 z2[4];
        #pragma unroll
        for (int t = 0; t < 4; ++t) z2[t] = f32x4{b2v[t], b2v[t], b2v[t], b2v[t]};
        #pragma unroll
        for (int ks = 0; ks < 2; ++ks) {
            const half8 a = *reinterpret_cast<const half8*>(
                &xw[col * XROW + g * 8 + ks * 32]);
            #pragma unroll
            for (int t = 0; t < 4; ++t)
                z2[t] = __builtin_amdgcn_mfma_f32_16x16x32_f16(a, wb[1][ks][t], z2[t], 0, 0, 0);
        }
        // energy partials + g2 = W3 * silu'(z2) -> xh
        float e0 = 0.f, e1 = 0.f, e2 = 0.f, e3 = 0.f;
        #pragma unroll
        for (int t = 0; t < 4; ++t)
            #pragma unroll
            for (int i = 0; i < 4; ++i) {
                const float z = z2[t][i];
                const float s = 1.f / (1.f + __expf(-z));
                const float h2 = z * s;
                const float ec = h2 * w3v[t];
                if (i == 0) e0 += ec; else if (i == 1) e1 += ec;
                else if (i == 2) e2 += ec; else e3 += ec;
                const float gv = w3v[t] * (s * (1.f + z * (1.f - s)));
                const float gn = __shfl_xor(gv, 1);
                if ((lane & 1) == 0)
                    *reinterpret_cast<unsigned*>(
                        &xw[(4 * g + i) * XROW + t * 16 + col]) = pk2h(gv, gn);
            }
        // reduce energy across the 16 cols
        float e[4] = {e0, e1, e2, e3};
        #pragma unroll
        for (int i = 0; i < 4; ++i) {
            e[i] += __shfl_xor(e[i], 1);
            e[i] += __shfl_xor(e[i], 2);
            e[i] += __shfl_xor(e[i], 4);
            e[i] += __shfl_xor(e[i], 8);
        }
        if (col == 0) {
            #pragma unroll
            for (int i = 0; i < 4; ++i) {
                const int atom = abase + 4 * g + i;
                if (atom < natoms) {
                    const int conf = indices[atom];
                    if (ldsE) atomicAdd(&esum[conf], e[i] + b3v);
                    else      unsafeAtomicAdd(&e_out[conf], e[i] + b3v);
                }
            }
        }

        // ---- bwd1: dh1 = G2 @ W2^T ----
        f32x4 dh[4];
        #pragma unroll
        for (int t = 0; t < 4; ++t) dh[t] = f32x4{0.f, 0.f, 0.f, 0.f};
        #pragma unroll
        for (int ks = 0; ks < 2; ++ks) {
            const half8 a = *reinterpret_cast<const half8*>(
                &xw[col * XROW + g * 8 + ks * 32]);
            #pragma unroll
            for (int t = 0; t < 4; ++t)
                dh[t] = __builtin_amdgcn_mfma_f32_16x16x32_f16(a, wb[2][ks][t], dh[t], 0, 0, 0);
        }
        // g1 = dh1 * silu'(z1) -> xh
        #pragma unroll
        for (int t = 0; t < 4; ++t)
            #pragma unroll
            for (int i = 0; i < 4; ++i) {
                const float z = z1[t][i];
                const float s = 1.f / (1.f + __expf(-z));
                const float gv = dh[t][i] * (s * (1.f + z * (1.f - s)));
                const float gn = __shfl_xor(gv, 1);
                if ((lane & 1) == 0)
                    *reinterpret_cast<unsigned*>(
                        &xw[(4 * g + i) * XROW + t * 16 + col]) = pk2h(gv, gn);
            }

        // ---- bwd2: dx = G1 @ W1^T ----
        f32x4 dx[4];
        #pragma unroll
        for (int t = 0; t < 4; ++t) dx[t] = f32x4{0.f, 0.f, 0.f, 0.f};
        #pragma unroll
        for (int ks = 0; ks < 2; ++ks) {
            const half8 a = *reinterpret_cast<const half8*>(
                &xw[col * XROW + g * 8 + ks * 32]);
            #pragma unroll
            for (int t = 0; t < 4; ++t)
                dx[t] = __builtin_amdgcn_mfma_f32_16x16x32_f16(a, wb[3][ks][t], dx[t], 0, 0, 0);
        }
        // dx -> xh (f16; cols 56..63 are zeros via zero B-frags)
        #pragma unroll
        for (int t = 0; t < 4; ++t)
            #pragma unroll
            for (int i = 0; i < 4; ++i) {
                const float v = dx[t][i];
                const float vn = __shfl_xor(v, 1);
                if ((lane & 1) == 0)
                    *reinterpret_cast<unsigned*>(
                        &xw[(4 * g + i) * XROW + t * 16 + col]) = pk2h(v, vn);
            }
        // coalesced readout -> dEdD (128B rows)
        #pragma unroll
        for (int c = 0; c < 2; ++c) {
            const int atom = lane >> 2;
            const int seg = (lane & 3) * 2 + c;
            const half8 vv = *reinterpret_cast<const half8*>(&xw[atom * XROW + seg * 8]);
            if (abase + atom < natoms)
                *reinterpret_cast<half8*>(
                    &dEdD[(size_t)(abase + atom) * 64 + seg * 8]) = vv;
        }
    }

    __syncthreads();
    if (ldsE) {
        for (int c = tid; c < nconf; c += 256) {
            const float v = esum[c];
            if (v != 0.f) unsafeAtomicAdd(&e_out[c], v);
        }
    }
}

// Grid-strided force kernel (round-12 exact: best at 325us total).
__global__ __launch_bounds__(256) void force_kernel(
    const float* __restrict__ xd,       // [M*ND]
    const int*   __restrict__ xd_indx,  // [M*3]
    const int*   __restrict__ unique_j, // [M]
    const _Float16* __restrict__ dEdD,  // [natoms*64] halfs
    float* __restrict__ out_f,          // [3*natoms] (pre-zeroed d_out region)
    int M, int CH)
{
    const int b = blockIdx.x, tid = threadIdx.x;
    const int team = tid >> 4, sub = tid & 15;   // 16 teams/block
    const int mstart = b * CH;
    const int mend   = min(mstart + CH, M);

    for (int m0 = mstart; m0 < mend; m0 += 16) {
        const int m = m0 + team;
        float partial = 0.f;
        const bool act = (m < mend);
        if (act && sub < 14) {
            const int a = __builtin_nontemporal_load(xd_indx + 3 * (size_t)m);
            const v4f u = __builtin_nontemporal_load(
                reinterpret_cast<const v4f*>(xd) + (size_t)m * 14 + sub);
            const v4h hv = reinterpret_cast<const v4h*>(dEdD + ((size_t)a << 6))[sub];
            partial = fmaf(u.x, (float)hv.x,
                      fmaf(u.y, (float)hv.y,
                      fmaf(u.z, (float)hv.z, u.w * (float)hv.w)));
        }
        partial += __shfl_xor(partial, 1);
        partial += __shfl_xor(partial, 2);
        partial += __shfl_xor(partial, 4);
        partial += __shfl_xor(partial, 8);

        if (act && sub == 0) {
            const int coord = __builtin_nontemporal_load(xd_indx + 3 * (size_t)m + 2);
            const int j     = __builtin_nontemporal_load(unique_j + m);
            unsafeAtomicAdd(&out_f[(size_t)j * 3 + coord], partial);
        }
    }
}

extern "C" void kernel_launch(void* const* d_in, const int* in_sizes, int n_in,
                              void* d_out, int out_size, void* d_ws, size_t ws_size,
                              hipStream_t stream) {
    const float* x        = (const float*)d_in[0];
    const float* xd       = (const float*)d_in[1];
    const int*   indices  = (const int*)d_in[2];
    const int*   xd_indx  = (const int*)d_in[4];
    const int*   unique_j = (const int*)d_in[5];
    const float* W1 = (const float*)d_in[6];
    const float* b1 = (const float*)d_in[7];
    const float* W2 = (const float*)d_in[8];
    const float* b2 = (const float*)d_in[9];
    const float* W3 = (const float*)d_in[10];
    const float* b3 = (const float*)d_in[11];

    const int natoms = in_sizes[0] / ND;
    const int M      = in_sizes[1] / ND;
    const int nconf  = in_sizes[3];

    float*    out_e = (float*)d_out;           // [nconf]
    float*    out_f = out_e + nconf;           // [3*natoms]
    _Float16* dEdDh = (_Float16*)d_ws;         // [natoms*64] halfs (6.4 MB)

    // d_out is poisoned once before timing; zero it every call.
    zero_kernel<<<(out_size + 255) / 256, 256, 0, stream>>>((float*)d_out, out_size);

    mlp_kernel<<<512, 256, 0, stream>>>(
        x, indices, W1, b1, W2, b2, W3, b3, out_e, dEdDh, natoms, nconf);

    const int CH = (M + FBLK - 1) / FBLK;
    force_kernel<<<FBLK, 256, 0, stream>>>(
        xd, xd_indx, unique_j, dEdDh, out_f, M, CH);
}